// Round 3
// baseline (113700.171 us; speedup 1.0000x reference)
//
#include <hip/hip_runtime.h>
#include <hip/hip_bf16.h>
#include <hip/hip_cooperative_groups.h>

namespace cg = cooperative_groups;

// HierESN (fp32 I/O): out[t] = [v1(t)|v2(t)], v' = .5v + .5tanh(v@W + u@Win)
// A: U = X @ Win1 (bf16 MFMA)           B: coop scan layer1 (1 kernel, grid.sync/step)
// C: U = V1bf @ Win2 (bf16 MFMA)        D: coop scan layer2
// W1/W2 ~90% sparse -> per-block packed {bf16<<16|row}, layout [b][slot][jl]
// (8 cols/block) so packed reads are 256B-coalesced and L2-resident per block.

typedef __bf16 bf16;
typedef __bf16 bf16x8 __attribute__((ext_vector_type(8)));
typedef float  f32x4  __attribute__((ext_vector_type(4)));

#define RDIM 4000
#define TSTEPS 1000
#define CAP 640            // slots per column (binomial(4000,0.1) max ~475)
#define NBLK 500           // scan blocks: 8 cols each
#define CH 8               // compress row-chunks (500 rows each)

__device__ inline unsigned pack_rne(float w, unsigned row) {
    unsigned u = __float_as_uint(w);
    return ((u + 0x7FFFu + ((u >> 16) & 1u)) & 0xFFFF0000u) | row;
}

// ---- compress pass 1: nnz count per (chunk, col) ----
__global__ __launch_bounds__(256) void count_k(const float* __restrict__ W,
                                               unsigned* __restrict__ cnts) {
    int j = blockIdx.x * 256 + threadIdx.x;
    int c = blockIdx.y;
    if (j >= RDIM) return;
    unsigned n = 0;
    const float* p = W + (size_t)c * 500 * RDIM + j;
    for (int i = 0; i < 500; i++) n += (p[(size_t)i * RDIM] != 0.0f);
    cnts[c * RDIM + j] = n;
}

// ---- compress pass 2: exclusive prefix over chunks; totals -> cnts[0..RDIM) ----
__global__ __launch_bounds__(256) void offs_k(unsigned* __restrict__ cnts,
                                              unsigned* __restrict__ offs) {
    int j = blockIdx.x * 256 + threadIdx.x;
    if (j >= RDIM) return;
    unsigned run = 0;
    for (int c = 0; c < CH; c++) {
        offs[c * RDIM + j] = run;
        run += cnts[c * RDIM + j];
    }
    cnts[j] = run;   // total nnz for col j (cnts[0][*] already consumed)
}

// ---- compress pass 3: per-block loop bound ----
__global__ __launch_bounds__(256) void kmax_k(const unsigned* __restrict__ totals,
                                              int* __restrict__ kmax) {
    int b = blockIdx.x * 256 + threadIdx.x;
    if (b >= NBLK) return;
    unsigned m = 0;
    for (int jl = 0; jl < 8; jl++) {
        unsigned t = totals[b * 8 + jl];
        m = t > m ? t : m;
    }
    kmax[b] = (int)(m < CAP ? m : CAP);
}

// ---- compress pass 4: fill packed [b][slot][jl]; pad slots pre-zeroed by memset ----
__global__ __launch_bounds__(256) void fill_k(const float* __restrict__ W,
                                              const unsigned* __restrict__ offs,
                                              unsigned* __restrict__ P) {
    int j = blockIdx.x * 256 + threadIdx.x;
    int c = blockIdx.y;
    if (j >= RDIM) return;
    unsigned slot = offs[c * RDIM + j];
    unsigned base = (unsigned)(j >> 3) * (CAP * 8) + (unsigned)(j & 7);
    int r0 = c * 500;
    for (int i = 0; i < 500; i++) {
        float w = W[(size_t)(r0 + i) * RDIM + j];
        if (w != 0.0f) {
            if (slot < CAP) P[base + slot * 8] = pack_rne(w, (unsigned)(r0 + i));
            slot++;
        }
    }
}

// ---- MFMA GEMM: C_f32[M,N] = A[M,K] @ B_f32[K,N] (A fp32 or bf16, staged bf16) ----
#define BM 64
#define BN 64
#define BK 32
#define LDP 56

__device__ inline bf16x8 load8(const float* p) {
    const f32x4* q = (const f32x4*)p;
    f32x4 f0 = q[0], f1 = q[1];
    bf16x8 r;
    r[0] = (bf16)f0[0]; r[1] = (bf16)f0[1]; r[2] = (bf16)f0[2]; r[3] = (bf16)f0[3];
    r[4] = (bf16)f1[0]; r[5] = (bf16)f1[1]; r[6] = (bf16)f1[2]; r[7] = (bf16)f1[3];
    return r;
}
__device__ inline bf16x8 load8(const bf16* p) { return *(const bf16x8*)p; }

template <typename AT>
__global__ __launch_bounds__(256) void gemm_k(const AT* __restrict__ A,
                                              const float* __restrict__ B,
                                              float* __restrict__ C,
                                              int M, int N, int K,
                                              int lda, int ldb, int ldc) {
    __shared__ bf16 As[BM][LDP];
    __shared__ bf16 Bs[BN][LDP];
    int tid  = threadIdx.x;
    int wave = tid >> 6, lane = tid & 63;
    int q    = lane >> 4;
    int l16  = lane & 15;
    int m0 = blockIdx.y * BM;
    int n0 = blockIdx.x * BN;

    int arow = tid >> 2;
    int acol = (tid & 3) * 8;
    int brow = tid >> 3;
    int bcol = (tid & 7) * 8;

    f32x4 acc[4];
    for (int nb = 0; nb < 4; nb++) for (int r = 0; r < 4; r++) acc[nb][r] = 0.f;

    for (int k0 = 0; k0 < K; k0 += BK) {
        bf16x8 av; for (int e = 0; e < 8; e++) av[e] = (bf16)0.f;
        if (m0 + arow < M)
            av = load8(A + (size_t)(m0 + arow) * lda + k0 + acol);
        bf16x8 bv;
        if (n0 + bcol + 8 <= N)
            bv = load8(B + (size_t)(k0 + brow) * ldb + n0 + bcol);
        else {
            for (int e = 0; e < 8; e++) {
                int col = n0 + bcol + e;
                bv[e] = (col < N) ? (bf16)B[(size_t)(k0 + brow) * ldb + col] : (bf16)0.f;
            }
        }
        __syncthreads();
        *(bf16x8*)&As[arow][acol] = av;
        for (int e = 0; e < 8; e++) Bs[bcol + e][brow] = bv[e];
        __syncthreads();

        bf16x8 af = *(const bf16x8*)&As[wave * 16 + l16][q * 8];
        #pragma unroll
        for (int nb = 0; nb < 4; nb++) {
            bf16x8 bfr = *(const bf16x8*)&Bs[nb * 16 + l16][q * 8];
            acc[nb] = __builtin_amdgcn_mfma_f32_16x16x32_bf16(af, bfr, acc[nb], 0, 0, 0);
        }
    }
    for (int nb = 0; nb < 4; nb++)
        for (int r = 0; r < 4; r++) {
            int row = m0 + wave * 16 + q * 4 + r;   // C/D: col=lane&15, row=q*4+r [m89]
            int col = n0 + nb * 16 + l16;
            if (row < M && col < N) C[(size_t)row * ldc + col] = acc[nb][r];
        }
}

// ---- persistent cooperative scan: all T steps, grid.sync between steps ----
// NBLK blocks x 256 thr; block b owns cols [8b,8b+8); thread: jl=tid&7, ks=tid>>3.
__global__ __launch_bounds__(256, 2) void scan_coop(
        const unsigned* __restrict__ P, const int* __restrict__ kmax,
        const float* __restrict__ U, float* __restrict__ va, float* __restrict__ vb,
        float* __restrict__ outbase, bf16* __restrict__ vhist) {
    cg::grid_group grid = cg::this_grid();
    __shared__ __align__(16) float vsh[RDIM];
    __shared__ float red[256];
    int tid = threadIdx.x, b = blockIdx.x;
    int jl = tid & 7, ks = tid >> 3;
    const unsigned* Pb = P + (size_t)b * (CAP * 8);
    int kb = kmax[b];

    for (int t = 0; t < TSTEPS; t++) {
        const float* vo = (t & 1) ? vb : va;
        float*       vn = (t & 1) ? va : vb;
        for (int i = tid; i < RDIM / 4; i += 256)
            ((f32x4*)vsh)[i] = ((const f32x4*)vo)[i];
        __syncthreads();

        float acc = 0.f;
        for (int k = ks; k < kb; k += 32) {
            unsigned p = Pb[k * 8 + jl];                       // 256B-coalesced, L2-hot
            acc += vsh[p & 0xFFFFu] * __uint_as_float(p & 0xFFFF0000u);
        }
        red[tid] = acc;
        __syncthreads();
        if (tid < 8) {
            float s = 0.f;
            #pragma unroll
            for (int c = 0; c < 32; c++) s += red[c * 8 + tid];
            int j = b * 8 + tid;
            float vnj = 0.5f * vsh[j] + 0.5f * tanhf(s + U[(size_t)t * RDIM + j]);
            vn[j] = vnj;
            outbase[(size_t)t * 8000 + j] = vnj;
            if (vhist) vhist[(size_t)t * RDIM + j] = (bf16)vnj;
        }
        grid.sync();   // barrier + device-scope visibility of vn
    }
}

// ---- launch ----
extern "C" void kernel_launch(void* const* d_in, const int* in_sizes, int n_in,
                              void* d_out, int out_size, void* d_ws, size_t ws_size,
                              hipStream_t stream) {
    const float* x    = (const float*)d_in[0];   // [1000][4096]
    const float* Win1 = (const float*)d_in[1];   // [4096][4000]
    const float* W1   = (const float*)d_in[2];   // [4000][4000]
    const float* Win2 = (const float*)d_in[3];   // [4000][4000]
    const float* W2   = (const float*)d_in[4];   // [4000][4000]
    float* out = (float*)d_out;                  // [1000][8000]

    char* ws = (char*)d_ws;
    // ws: U 16,000,000 (head doubles as cnts/offs scratch pre-GEMM)
    //     P1 10,240,000 | P2 10,240,000 | V1bf 8,000,000
    //     kmax1 2,000 | kmax2 2,000 | vbuf 64,000   (total 44,548,000 B)
    float*    U     = (float*)(ws);
    unsigned* cnts  = (unsigned*)(ws);                 // [8][4000], dead after compress
    unsigned* offs  = (unsigned*)(ws + 128000);        // [8][4000], dead after compress
    unsigned* P1    = (unsigned*)(ws + 16000000);
    unsigned* P2    = (unsigned*)(ws + 26240000);
    bf16*     V1bf  = (bf16*)(ws + 36480000);          // [1000][4000]
    int*      kmax1 = (int*)(ws + 44480000);
    int*      kmax2 = (int*)(ws + 44482000);
    float*    vbuf  = (float*)(ws + 44484000);         // [4][4000]

    hipMemsetAsync(vbuf, 0, 4 * RDIM * sizeof(float), stream);
    hipMemsetAsync(P1, 0, (size_t)NBLK * CAP * 8 * 4, stream);
    hipMemsetAsync(P2, 0, (size_t)NBLK * CAP * 8 * 4, stream);

    dim3 cg16(16, CH);
    // compress W1 then W2 (scratch in U region, consumed before gemm1 writes U)
    count_k<<<cg16, 256, 0, stream>>>(W1, cnts);
    offs_k<<<16, 256, 0, stream>>>(cnts, offs);
    kmax_k<<<2, 256, 0, stream>>>(cnts, kmax1);
    fill_k<<<cg16, 256, 0, stream>>>(W1, offs, P1);
    count_k<<<cg16, 256, 0, stream>>>(W2, cnts);
    offs_k<<<16, 256, 0, stream>>>(cnts, offs);
    kmax_k<<<2, 256, 0, stream>>>(cnts, kmax2);
    fill_k<<<cg16, 256, 0, stream>>>(W2, offs, P2);

    dim3 gg((RDIM + BN - 1) / BN, (TSTEPS + BM - 1) / BM);
    gemm_k<float><<<gg, 256, 0, stream>>>(x, Win1, U, TSTEPS, RDIM, 4096,
                                          4096, RDIM, RDIM);

    {   // scan layer 1
        const unsigned* Pp = P1; const int* km = kmax1; const float* Up = U;
        float* va = vbuf; float* vb = vbuf + RDIM;
        float* ob = out; bf16* vh = V1bf;
        void* args[] = {&Pp, &km, &Up, &va, &vb, &ob, &vh};
        hipLaunchCooperativeKernel((void*)scan_coop, dim3(NBLK), dim3(256),
                                   args, 0, stream);
    }

    gemm_k<bf16><<<gg, 256, 0, stream>>>(V1bf, Win2, U, TSTEPS, RDIM, RDIM,
                                         RDIM, RDIM, RDIM);

    {   // scan layer 2
        const unsigned* Pp = P2; const int* km = kmax2; const float* Up = U;
        float* va = vbuf + 2 * RDIM; float* vb = vbuf + 3 * RDIM;
        float* ob = out + RDIM; bf16* vh = nullptr;
        void* args[] = {&Pp, &km, &Up, &va, &vb, &ob, &vh};
        hipLaunchCooperativeKernel((void*)scan_coop, dim3(NBLK), dim3(256),
                                   args, 0, stream);
    }
}

// Round 4
// 33138.824 us; speedup vs baseline: 3.4310x; 3.4310x over previous
//
#include <hip/hip_runtime.h>
#include <hip/hip_bf16.h>

// HierESN (fp32 I/O): out[t] = [v1(t)|v2(t)], v' = .5v + .5tanh(v@W + u@Win)
// A: U = X @ Win1 (bf16 MFMA)      B: persistent coop scan layer1 (custom barrier)
// C: U = V1bf @ Win2 (bf16 MFMA)   D: persistent coop scan layer2
// W1/W2 ~90% sparse -> per-block packed {bf16<<16|row}, layout [b][slot][jl],
// 8 cols/block, 256B-coalesced, L2-resident (barrier does NO cache invalidate).
// Cross-step v exchange via agent-scope (sc0 sc1) loads/stores through L3.

typedef __bf16 bf16;
typedef __bf16 bf16x8 __attribute__((ext_vector_type(8)));
typedef float  f32x4  __attribute__((ext_vector_type(4)));

#define RDIM 4000
#define TSTEPS 1000
#define CAP 640            // slots per column (binomial(4000,0.1) max ~475)
#define NBLK 500           // scan blocks: 8 cols each
#define CH 8               // compress row-chunks (500 rows each)

__device__ inline unsigned pack_rne(float w, unsigned row) {
    unsigned u = __float_as_uint(w);
    return ((u + 0x7FFFu + ((u >> 16) & 1u)) & 0xFFFF0000u) | row;
}

// ---- compress pass 1: nnz count per (chunk, col) ----
__global__ __launch_bounds__(256) void count_k(const float* __restrict__ W,
                                               unsigned* __restrict__ cnts) {
    int j = blockIdx.x * 256 + threadIdx.x;
    int c = blockIdx.y;
    if (j >= RDIM) return;
    unsigned n = 0;
    const float* p = W + (size_t)c * 500 * RDIM + j;
    for (int i = 0; i < 500; i++) n += (p[(size_t)i * RDIM] != 0.0f);
    cnts[c * RDIM + j] = n;
}

// ---- compress pass 2: exclusive prefix over chunks; totals -> cnts[0..RDIM) ----
__global__ __launch_bounds__(256) void offs_k(unsigned* __restrict__ cnts,
                                              unsigned* __restrict__ offs) {
    int j = blockIdx.x * 256 + threadIdx.x;
    if (j >= RDIM) return;
    unsigned run = 0;
    for (int c = 0; c < CH; c++) {
        offs[c * RDIM + j] = run;
        run += cnts[c * RDIM + j];
    }
    cnts[j] = run;
}

// ---- compress pass 3: per-block loop bound ----
__global__ __launch_bounds__(256) void kmax_k(const unsigned* __restrict__ totals,
                                              int* __restrict__ kmax) {
    int b = blockIdx.x * 256 + threadIdx.x;
    if (b >= NBLK) return;
    unsigned m = 0;
    for (int jl = 0; jl < 8; jl++) {
        unsigned t = totals[b * 8 + jl];
        m = t > m ? t : m;
    }
    kmax[b] = (int)(m < CAP ? m : CAP);
}

// ---- compress pass 4: fill packed [b][slot][jl]; pad slots pre-zeroed by memset ----
__global__ __launch_bounds__(256) void fill_k(const float* __restrict__ W,
                                              const unsigned* __restrict__ offs,
                                              unsigned* __restrict__ P) {
    int j = blockIdx.x * 256 + threadIdx.x;
    int c = blockIdx.y;
    if (j >= RDIM) return;
    unsigned slot = offs[c * RDIM + j];
    unsigned base = (unsigned)(j >> 3) * (CAP * 8) + (unsigned)(j & 7);
    int r0 = c * 500;
    for (int i = 0; i < 500; i++) {
        float w = W[(size_t)(r0 + i) * RDIM + j];
        if (w != 0.0f) {
            if (slot < CAP) P[base + slot * 8] = pack_rne(w, (unsigned)(r0 + i));
            slot++;
        }
    }
}

// ---- MFMA GEMM: C_f32[M,N] = A[M,K] @ B_f32[K,N] (A fp32 or bf16, staged bf16) ----
#define BM 64
#define BN 64
#define BK 32
#define LDP 56

__device__ inline bf16x8 load8(const float* p) {
    const f32x4* q = (const f32x4*)p;
    f32x4 f0 = q[0], f1 = q[1];
    bf16x8 r;
    r[0] = (bf16)f0[0]; r[1] = (bf16)f0[1]; r[2] = (bf16)f0[2]; r[3] = (bf16)f0[3];
    r[4] = (bf16)f1[0]; r[5] = (bf16)f1[1]; r[6] = (bf16)f1[2]; r[7] = (bf16)f1[3];
    return r;
}
__device__ inline bf16x8 load8(const bf16* p) { return *(const bf16x8*)p; }

template <typename AT>
__global__ __launch_bounds__(256) void gemm_k(const AT* __restrict__ A,
                                              const float* __restrict__ B,
                                              float* __restrict__ C,
                                              int M, int N, int K,
                                              int lda, int ldb, int ldc) {
    __shared__ bf16 As[BM][LDP];
    __shared__ bf16 Bs[BN][LDP];
    int tid  = threadIdx.x;
    int wave = tid >> 6, lane = tid & 63;
    int q    = lane >> 4;
    int l16  = lane & 15;
    int m0 = blockIdx.y * BM;
    int n0 = blockIdx.x * BN;

    int arow = tid >> 2;
    int acol = (tid & 3) * 8;
    int brow = tid >> 3;
    int bcol = (tid & 7) * 8;

    f32x4 acc[4];
    for (int nb = 0; nb < 4; nb++) for (int r = 0; r < 4; r++) acc[nb][r] = 0.f;

    for (int k0 = 0; k0 < K; k0 += BK) {
        bf16x8 av; for (int e = 0; e < 8; e++) av[e] = (bf16)0.f;
        if (m0 + arow < M)
            av = load8(A + (size_t)(m0 + arow) * lda + k0 + acol);
        bf16x8 bv;
        if (n0 + bcol + 8 <= N)
            bv = load8(B + (size_t)(k0 + brow) * ldb + n0 + bcol);
        else {
            for (int e = 0; e < 8; e++) {
                int col = n0 + bcol + e;
                bv[e] = (col < N) ? (bf16)B[(size_t)(k0 + brow) * ldb + col] : (bf16)0.f;
            }
        }
        __syncthreads();
        *(bf16x8*)&As[arow][acol] = av;
        for (int e = 0; e < 8; e++) Bs[bcol + e][brow] = bv[e];
        __syncthreads();

        bf16x8 af = *(const bf16x8*)&As[wave * 16 + l16][q * 8];
        #pragma unroll
        for (int nb = 0; nb < 4; nb++) {
            bf16x8 bfr = *(const bf16x8*)&Bs[nb * 16 + l16][q * 8];
            acc[nb] = __builtin_amdgcn_mfma_f32_16x16x32_bf16(af, bfr, acc[nb], 0, 0, 0);
        }
    }
    for (int nb = 0; nb < 4; nb++)
        for (int r = 0; r < 4; r++) {
            int row = m0 + wave * 16 + q * 4 + r;   // C/D: col=lane&15, row=q*4+r [m89]
            int col = n0 + nb * 16 + l16;
            if (row < M && col < N) C[(size_t)row * ldc + col] = acc[nb][r];
        }
}

// ---- persistent scan with custom lockstep barrier ----
// NBLK blocks x 256 thr; block b owns cols [8b,8b+8); jl=tid&7, ks=tid>>3.
// barrier: monotone arrival counters cnt[8] (stride 8 dwords), agent-scope only;
// no acquire fence -> packed P stays L2-cached; v goes through L3 via sc loads.
__global__ __launch_bounds__(256, 2) void scan_coop(
        const unsigned* __restrict__ P, const int* __restrict__ kmax,
        const float* __restrict__ U, float* __restrict__ va, float* __restrict__ vb,
        float* __restrict__ outbase, bf16* __restrict__ vhist,
        unsigned* __restrict__ cnt) {
    __shared__ __align__(16) float vsh[RDIM];
    __shared__ float red[256];
    int tid = threadIdx.x, b = blockIdx.x;
    int jl = tid & 7, ks = tid >> 3;
    const unsigned* Pb = P + (size_t)b * (CAP * 8);
    int kb = kmax[b];

    for (int t = 0; t < TSTEPS; t++) {
        const float* vo = (t & 1) ? vb : va;
        float*       vn = (t & 1) ? va : vb;

        if (t > 0) {                         // wait: all blocks finished step t-1
            if (tid == 0) {
                unsigned target = (unsigned)NBLK * (unsigned)t;
                for (;;) {
                    unsigned s = 0;
                    #pragma unroll
                    for (int i = 0; i < 8; i++)
                        s += __hip_atomic_load(cnt + i * 8, __ATOMIC_RELAXED,
                                               __HIP_MEMORY_SCOPE_AGENT);
                    if (s >= target) break;
                    __builtin_amdgcn_s_sleep(1);
                }
            }
            __syncthreads();
        }

        // stage v into LDS via agent-scope loads (bypass stale L1/L2)
        for (int i = tid; i < RDIM; i += 256)
            vsh[i] = __hip_atomic_load(vo + i, __ATOMIC_RELAXED,
                                       __HIP_MEMORY_SCOPE_AGENT);
        __syncthreads();

        float acc = 0.f;
        for (int k = ks; k < kb; k += 32) {
            unsigned p = Pb[k * 8 + jl];                       // L2-hot, coalesced
            acc += vsh[p & 0xFFFFu] * __uint_as_float(p & 0xFFFF0000u);
        }
        red[tid] = acc;
        __syncthreads();
        if (tid < 8) {
            float s = 0.f;
            #pragma unroll
            for (int c = 0; c < 32; c++) s += red[c * 8 + tid];
            int j = b * 8 + tid;
            float vnj = 0.5f * vsh[j] + 0.5f * tanhf(s + U[(size_t)t * RDIM + j]);
            __hip_atomic_store(vn + j, vnj, __ATOMIC_RELAXED,
                               __HIP_MEMORY_SCOPE_AGENT);     // straight to L3
            outbase[(size_t)t * 8000 + j] = vnj;
            if (vhist) vhist[(size_t)t * RDIM + j] = (bf16)vnj;
        }
        __syncthreads();                     // vmcnt(0): vn stores drained
        if (tid == 0)
            __hip_atomic_fetch_add(cnt + (b & 7) * 8, 1u, __ATOMIC_RELAXED,
                                   __HIP_MEMORY_SCOPE_AGENT);
    }
}

// ---- launch ----
extern "C" void kernel_launch(void* const* d_in, const int* in_sizes, int n_in,
                              void* d_out, int out_size, void* d_ws, size_t ws_size,
                              hipStream_t stream) {
    const float* x    = (const float*)d_in[0];   // [1000][4096]
    const float* Win1 = (const float*)d_in[1];   // [4096][4000]
    const float* W1   = (const float*)d_in[2];   // [4000][4000]
    const float* Win2 = (const float*)d_in[3];   // [4000][4000]
    const float* W2   = (const float*)d_in[4];   // [4000][4000]
    float* out = (float*)d_out;                  // [1000][8000]

    char* ws = (char*)d_ws;
    // ws: U 16,000,000 (head doubles as cnts/offs scratch pre-GEMM)
    //     P1 10,240,000 | P2 10,240,000 | V1bf 8,000,000
    //     kmax1 2,000 | kmax2 2,000 | vbuf 64,000 | cnt1/cnt2 512
    float*    U     = (float*)(ws);
    unsigned* cnts  = (unsigned*)(ws);                 // [8][4000], dead after compress
    unsigned* offs  = (unsigned*)(ws + 128000);        // [8][4000], dead after compress
    unsigned* P1    = (unsigned*)(ws + 16000000);
    unsigned* P2    = (unsigned*)(ws + 26240000);
    bf16*     V1bf  = (bf16*)(ws + 36480000);          // [1000][4000]
    int*      kmax1 = (int*)(ws + 44480000);
    int*      kmax2 = (int*)(ws + 44482000);
    float*    vbuf  = (float*)(ws + 44484000);         // [4][4000]
    unsigned* cnt1  = (unsigned*)(ws + 44548000);      // 8 counters, stride 8 dw
    unsigned* cnt2  = (unsigned*)(ws + 44548256);

    hipMemsetAsync(vbuf, 0, 4 * RDIM * sizeof(float), stream);
    hipMemsetAsync(cnt1, 0, 512, stream);
    hipMemsetAsync(P1, 0, (size_t)NBLK * CAP * 8 * 4, stream);
    hipMemsetAsync(P2, 0, (size_t)NBLK * CAP * 8 * 4, stream);

    dim3 cg16(16, CH);
    count_k<<<cg16, 256, 0, stream>>>(W1, cnts);
    offs_k<<<16, 256, 0, stream>>>(cnts, offs);
    kmax_k<<<2, 256, 0, stream>>>(cnts, kmax1);
    fill_k<<<cg16, 256, 0, stream>>>(W1, offs, P1);
    count_k<<<cg16, 256, 0, stream>>>(W2, cnts);
    offs_k<<<16, 256, 0, stream>>>(cnts, offs);
    kmax_k<<<2, 256, 0, stream>>>(cnts, kmax2);
    fill_k<<<cg16, 256, 0, stream>>>(W2, offs, P2);

    dim3 gg((RDIM + BN - 1) / BN, (TSTEPS + BM - 1) / BM);
    gemm_k<float><<<gg, 256, 0, stream>>>(x, Win1, U, TSTEPS, RDIM, 4096,
                                          4096, RDIM, RDIM);

    {   // scan layer 1
        const unsigned* Pp = P1; const int* km = kmax1; const float* Up = U;
        float* va = vbuf; float* vb = vbuf + RDIM;
        float* ob = out; bf16* vh = V1bf; unsigned* cn = cnt1;
        void* args[] = {&Pp, &km, &Up, &va, &vb, &ob, &vh, &cn};
        hipLaunchCooperativeKernel((void*)scan_coop, dim3(NBLK), dim3(256),
                                   args, 0, stream);
    }

    gemm_k<bf16><<<gg, 256, 0, stream>>>(V1bf, Win2, U, TSTEPS, RDIM, RDIM,
                                         RDIM, RDIM, RDIM);

    {   // scan layer 2
        const unsigned* Pp = P2; const int* km = kmax2; const float* Up = U;
        float* va = vbuf + 2 * RDIM; float* vb = vbuf + 3 * RDIM;
        float* ob = out + RDIM; bf16* vh = nullptr; unsigned* cn = cnt2;
        void* args[] = {&Pp, &km, &Up, &va, &vb, &ob, &vh, &cn};
        hipLaunchCooperativeKernel((void*)scan_coop, dim3(NBLK), dim3(256),
                                   args, 0, stream);
    }
}

// Round 5
// 7651.678 us; speedup vs baseline: 14.8595x; 4.3309x over previous
//
#include <hip/hip_runtime.h>
#include <hip/hip_bf16.h>

// HierESN (fp32 I/O): out[t] = [v1(t)|v2(t)], v' = .5v + .5tanh(v@W + u@Win)
// A: U = X @ Win1 (bf16 MFMA)      B: persistent coop scan layer1 (custom barrier)
// C: U = V1bf @ Win2 (bf16 MFMA)   D: persistent coop scan layer2
// Scan: 250 blocks x 512 thr, 16 cols/block. Packed sparse W per block as
// [slotgroup][col][4slots] so gather loads are uint4 (1KB/wave). Cross-step v
// via agent-scope loads/stores (L3 coherence point); custom monotone-counter
// barrier (no cache invalidate -> P stays L2-resident).

typedef __bf16 bf16;
typedef __bf16 bf16x8 __attribute__((ext_vector_type(8)));
typedef float  f32x4  __attribute__((ext_vector_type(4)));
typedef unsigned uint4v __attribute__((ext_vector_type(4)));

#define RDIM 4000
#define TSTEPS 1000
#define CAP 640            // slots per column (binomial(4000,0.1) max ~475)
#define NBLK 250           // scan blocks
#define CB 16              // cols per block
#define CH 8               // compress row-chunks (500 rows each)

__device__ inline unsigned pack_rne(float w, unsigned row) {
    unsigned u = __float_as_uint(w);
    return ((u + 0x7FFFu + ((u >> 16) & 1u)) & 0xFFFF0000u) | row;
}

// ---- compress pass 1: nnz count per (chunk, col) ----
__global__ __launch_bounds__(256) void count_k(const float* __restrict__ W,
                                               unsigned* __restrict__ cnts) {
    int j = blockIdx.x * 256 + threadIdx.x;
    int c = blockIdx.y;
    if (j >= RDIM) return;
    unsigned n = 0;
    const float* p = W + (size_t)c * 500 * RDIM + j;
    for (int i = 0; i < 500; i++) n += (p[(size_t)i * RDIM] != 0.0f);
    cnts[c * RDIM + j] = n;
}

// ---- compress pass 2: exclusive prefix over chunks; totals -> cnts[0..RDIM) ----
__global__ __launch_bounds__(256) void offs_k(unsigned* __restrict__ cnts,
                                              unsigned* __restrict__ offs) {
    int j = blockIdx.x * 256 + threadIdx.x;
    if (j >= RDIM) return;
    unsigned run = 0;
    for (int c = 0; c < CH; c++) {
        offs[c * RDIM + j] = run;
        run += cnts[c * RDIM + j];
    }
    cnts[j] = run;
}

// ---- compress pass 3: per-block slot-group loop bound ----
__global__ __launch_bounds__(256) void kmax_k(const unsigned* __restrict__ totals,
                                              int* __restrict__ kmax) {
    int b = blockIdx.x * 256 + threadIdx.x;
    if (b >= NBLK) return;
    unsigned m = 0;
    for (int jl = 0; jl < CB; jl++) {
        unsigned t = totals[b * CB + jl];
        m = t > m ? t : m;
    }
    m = (m + 3) >> 2;                              // slot groups of 4
    kmax[b] = (int)(m < (CAP / 4) ? m : (CAP / 4));
}

// ---- compress pass 4: fill packed [b][sg][col][4]; pads pre-zeroed by memset ----
__global__ __launch_bounds__(256) void fill_k(const float* __restrict__ W,
                                              const unsigned* __restrict__ offs,
                                              unsigned* __restrict__ P) {
    int j = blockIdx.x * 256 + threadIdx.x;
    int c = blockIdx.y;
    if (j >= RDIM) return;
    unsigned slot = offs[c * RDIM + j];
    unsigned base = (unsigned)(j >> 4) * (CAP * CB) + (unsigned)(j & 15) * 4;
    int r0 = c * 500;
    for (int i = 0; i < 500; i++) {
        float w = W[(size_t)(r0 + i) * RDIM + j];
        if (w != 0.0f) {
            if (slot < CAP)
                P[base + (slot >> 2) * (CB * 4) + (slot & 3)] =
                    pack_rne(w, (unsigned)(r0 + i));
            slot++;
        }
    }
}

// ---- MFMA GEMM: C_f32[M,N] = A[M,K] @ B_f32[K,N] (A fp32 or bf16, staged bf16) ----
#define BM 64
#define BN 64
#define BK 32
#define LDP 56

__device__ inline bf16x8 load8(const float* p) {
    const f32x4* q = (const f32x4*)p;
    f32x4 f0 = q[0], f1 = q[1];
    bf16x8 r;
    r[0] = (bf16)f0[0]; r[1] = (bf16)f0[1]; r[2] = (bf16)f0[2]; r[3] = (bf16)f0[3];
    r[4] = (bf16)f1[0]; r[5] = (bf16)f1[1]; r[6] = (bf16)f1[2]; r[7] = (bf16)f1[3];
    return r;
}
__device__ inline bf16x8 load8(const bf16* p) { return *(const bf16x8*)p; }

template <typename AT>
__global__ __launch_bounds__(256) void gemm_k(const AT* __restrict__ A,
                                              const float* __restrict__ B,
                                              float* __restrict__ C,
                                              int M, int N, int K,
                                              int lda, int ldb, int ldc) {
    __shared__ bf16 As[BM][LDP];
    __shared__ bf16 Bs[BN][LDP];
    int tid  = threadIdx.x;
    int wave = tid >> 6, lane = tid & 63;
    int q    = lane >> 4;
    int l16  = lane & 15;
    int m0 = blockIdx.y * BM;
    int n0 = blockIdx.x * BN;

    int arow = tid >> 2;
    int acol = (tid & 3) * 8;
    int brow = tid >> 3;
    int bcol = (tid & 7) * 8;

    f32x4 acc[4];
    for (int nb = 0; nb < 4; nb++) for (int r = 0; r < 4; r++) acc[nb][r] = 0.f;

    for (int k0 = 0; k0 < K; k0 += BK) {
        bf16x8 av; for (int e = 0; e < 8; e++) av[e] = (bf16)0.f;
        if (m0 + arow < M)
            av = load8(A + (size_t)(m0 + arow) * lda + k0 + acol);
        bf16x8 bv;
        if (n0 + bcol + 8 <= N)
            bv = load8(B + (size_t)(k0 + brow) * ldb + n0 + bcol);
        else {
            for (int e = 0; e < 8; e++) {
                int col = n0 + bcol + e;
                bv[e] = (col < N) ? (bf16)B[(size_t)(k0 + brow) * ldb + col] : (bf16)0.f;
            }
        }
        __syncthreads();
        *(bf16x8*)&As[arow][acol] = av;
        for (int e = 0; e < 8; e++) Bs[bcol + e][brow] = bv[e];
        __syncthreads();

        bf16x8 af = *(const bf16x8*)&As[wave * 16 + l16][q * 8];
        #pragma unroll
        for (int nb = 0; nb < 4; nb++) {
            bf16x8 bfr = *(const bf16x8*)&Bs[nb * 16 + l16][q * 8];
            acc[nb] = __builtin_amdgcn_mfma_f32_16x16x32_bf16(af, bfr, acc[nb], 0, 0, 0);
        }
    }
    for (int nb = 0; nb < 4; nb++)
        for (int r = 0; r < 4; r++) {
            int row = m0 + wave * 16 + q * 4 + r;   // C/D: col=lane&15, row=q*4+r [m89]
            int col = n0 + nb * 16 + l16;
            if (row < M && col < N) C[(size_t)row * ldc + col] = acc[nb][r];
        }
}

// ---- persistent scan, custom lockstep barrier, batched bypass staging ----
// 250 blocks x 512 thr; block b owns cols [16b,16b+16); jl=tid&15, ks=tid>>4.
__global__ __launch_bounds__(512, 2) void scan_coop(
        const unsigned* __restrict__ P, const int* __restrict__ kmax,
        const float* __restrict__ U, float* __restrict__ va, float* __restrict__ vb,
        float* __restrict__ outbase, bf16* __restrict__ vhist,
        unsigned* __restrict__ cnt) {
    __shared__ __align__(16) float vsh[RDIM];
    __shared__ float red[8 * CB];
    int tid = threadIdx.x, b = blockIdx.x;
    int jl = tid & (CB - 1), ks = tid >> 4;          // ks 0..31
    const unsigned* Pb = P + (size_t)b * (CAP * CB);
    int kg = kmax[b];

    for (int t = 0; t < TSTEPS; t++) {
        const float* vo = (t & 1) ? vb : va;
        float*       vn = (t & 1) ? va : vb;

        if (t > 0) {                    // wait: all blocks finished step t-1
            if (tid == 0) {
                unsigned target = (unsigned)NBLK * (unsigned)t;
                for (;;) {
                    unsigned s = 0;
                    #pragma unroll
                    for (int i = 0; i < 8; i++)
                        s += __hip_atomic_load(cnt + i * 8, __ATOMIC_RELAXED,
                                               __HIP_MEMORY_SCOPE_AGENT);
                    if (s >= target) break;
                    __builtin_amdgcn_s_sleep(1);
                }
            }
            __syncthreads();
        }

        float uval = 0.f;               // prefetch U early (hides ~900cyc miss)
        if (tid < CB) uval = U[(size_t)t * RDIM + b * CB + tid];

        // batched bypass staging: 8 loads in flight, then LDS writes
        float rv[8];
        #pragma unroll
        for (int u = 0; u < 8; u++) {
            int i = (u << 9) + tid;
            int ic = i < RDIM ? i : (RDIM - 1);
            rv[u] = __hip_atomic_load(vo + ic, __ATOMIC_RELAXED,
                                      __HIP_MEMORY_SCOPE_AGENT);
        }
        #pragma unroll
        for (int u = 0; u < 8; u++) {
            int i = (u << 9) + tid;
            if (i < RDIM) vsh[i] = rv[u];
        }
        __syncthreads();

        float acc = 0.f;
        for (int sg = ks; sg < kg; sg += 32) {
            uint4v p = *(const uint4v*)(Pb + sg * (CB * 4) + jl * 4);  // L2-hot
            #pragma unroll
            for (int e = 0; e < 4; e++) {
                unsigned pe = p[e];
                acc += vsh[pe & 0xFFFFu] * __uint_as_float(pe & 0xFFFF0000u);
            }
        }
        // reduce ks within wave (4 ks values/wave share jl)
        acc += __shfl_xor(acc, 16, 64);
        acc += __shfl_xor(acc, 32, 64);
        int lane = tid & 63;
        if (lane < CB) red[(tid >> 6) * CB + lane] = acc;
        __syncthreads();
        if (tid < CB) {
            float s = 0.f;
            #pragma unroll
            for (int c = 0; c < 8; c++) s += red[c * CB + tid];
            int j = b * CB + tid;
            float vnj = 0.5f * vsh[j] + 0.5f * tanhf(s + uval);
            __hip_atomic_store(vn + j, vnj, __ATOMIC_RELAXED,
                               __HIP_MEMORY_SCOPE_AGENT);      // to L3
            outbase[(size_t)t * 8000 + j] = vnj;
            if (vhist) vhist[(size_t)t * RDIM + j] = (bf16)vnj;
        }
        __syncthreads();                // vmcnt(0): vn stores drained
        if (tid == 0)
            __hip_atomic_fetch_add(cnt + (b & 7) * 8, 1u, __ATOMIC_RELAXED,
                                   __HIP_MEMORY_SCOPE_AGENT);
    }
}

// ---- launch ----
extern "C" void kernel_launch(void* const* d_in, const int* in_sizes, int n_in,
                              void* d_out, int out_size, void* d_ws, size_t ws_size,
                              hipStream_t stream) {
    const float* x    = (const float*)d_in[0];   // [1000][4096]
    const float* Win1 = (const float*)d_in[1];   // [4096][4000]
    const float* W1   = (const float*)d_in[2];   // [4000][4000]
    const float* Win2 = (const float*)d_in[3];   // [4000][4000]
    const float* W2   = (const float*)d_in[4];   // [4000][4000]
    float* out = (float*)d_out;                  // [1000][8000]

    char* ws = (char*)d_ws;
    float*    U     = (float*)(ws);
    unsigned* cnts  = (unsigned*)(ws);                 // [8][4000], dead after compress
    unsigned* offs  = (unsigned*)(ws + 128000);        // [8][4000], dead after compress
    unsigned* P1    = (unsigned*)(ws + 16000000);
    unsigned* P2    = (unsigned*)(ws + 26240000);
    bf16*     V1bf  = (bf16*)(ws + 36480000);          // [1000][4000]
    int*      kmax1 = (int*)(ws + 44480000);
    int*      kmax2 = (int*)(ws + 44482000);
    float*    vbuf  = (float*)(ws + 44484000);         // [4][4000]
    unsigned* cnt1  = (unsigned*)(ws + 44548000);      // 8 counters, stride 8 dw
    unsigned* cnt2  = (unsigned*)(ws + 44548256);

    hipMemsetAsync(vbuf, 0, 4 * RDIM * sizeof(float), stream);
    hipMemsetAsync(cnt1, 0, 512, stream);              // covers cnt1+cnt2
    hipMemsetAsync(P1, 0, (size_t)NBLK * CAP * CB * 4, stream);
    hipMemsetAsync(P2, 0, (size_t)NBLK * CAP * CB * 4, stream);

    dim3 cg16(16, CH);
    count_k<<<cg16, 256, 0, stream>>>(W1, cnts);
    offs_k<<<16, 256, 0, stream>>>(cnts, offs);
    kmax_k<<<1, 256, 0, stream>>>(cnts, kmax1);
    fill_k<<<cg16, 256, 0, stream>>>(W1, offs, P1);
    count_k<<<cg16, 256, 0, stream>>>(W2, cnts);
    offs_k<<<16, 256, 0, stream>>>(cnts, offs);
    kmax_k<<<1, 256, 0, stream>>>(cnts, kmax2);
    fill_k<<<cg16, 256, 0, stream>>>(W2, offs, P2);

    dim3 gg((RDIM + BN - 1) / BN, (TSTEPS + BM - 1) / BM);
    gemm_k<float><<<gg, 256, 0, stream>>>(x, Win1, U, TSTEPS, RDIM, 4096,
                                          4096, RDIM, RDIM);

    {   // scan layer 1
        const unsigned* Pp = P1; const int* km = kmax1; const float* Up = U;
        float* va = vbuf; float* vb = vbuf + RDIM;
        float* ob = out; bf16* vh = V1bf; unsigned* cn = cnt1;
        void* args[] = {&Pp, &km, &Up, &va, &vb, &ob, &vh, &cn};
        hipLaunchCooperativeKernel((void*)scan_coop, dim3(NBLK), dim3(512),
                                   args, 0, stream);
    }

    gemm_k<bf16><<<gg, 256, 0, stream>>>(V1bf, Win2, U, TSTEPS, RDIM, RDIM,
                                         RDIM, RDIM, RDIM);

    {   // scan layer 2
        const unsigned* Pp = P2; const int* km = kmax2; const float* Up = U;
        float* va = vbuf + 2 * RDIM; float* vb = vbuf + 3 * RDIM;
        float* ob = out + RDIM; bf16* vh = nullptr; unsigned* cn = cnt2;
        void* args[] = {&Pp, &km, &Up, &va, &vb, &ob, &vh, &cn};
        hipLaunchCooperativeKernel((void*)scan_coop, dim3(NBLK), dim3(512),
                                   args, 0, stream);
    }
}